// Round 1
// baseline (120.298 us; speedup 1.0000x reference)
//
#include <hip/hip_runtime.h>

// FixedLearnableTensorSketch: B=4096, L=4096, A=4, D=128.
//
// R5: split the fused kernel into two stream-ordered dispatches.
//  - hist_kernel: pure 64 MiB sequence stream at max memory concurrency
//    (2048 blocks x 256 threads; 8 independent dwordx4 loads/thread).
//    Per-row counts are stashed in cols 0..3 of `out` (scratch) so we
//    don't depend on ws_size; each mlp block reads only the rows it
//    later overwrites -> no cross-block hazard.
//  - mlp_kernel: phases 2-4. Restructured thread mapping: each thread
//    owns 2 output columns (jg, jg+64) x one k-quarter (wave id), so the
//    LDS e-broadcast reads are reused across both columns: 128
//    ds_read_b128/thread vs 256 in the fused R4 kernel.
//
// Rationale: R4's single fused kernel measured 122.3 us; the roofline is
// ~11 us (stream) + ~5-8 us (MLP). Fusion serialized stream->MLP within
// each of only 2 resident blocks/CU, capping streaming concurrency and
// leaving HBM idle during the MLP tail.

static constexpr int Lc = 4096;
static constexpr int Ac = 4;
static constexpr int Dc = 128;

// ---------------- Kernel 1: per-row histogram ----------------
// 2 rows per block, 256 threads. Packed 4x16-bit counters in a u64:
// per-thread field max = 16, per-wave 1024, per-row total 4096 < 2^16.
static constexpr int HROWS = 2;

__global__ __launch_bounds__(256, 4)
void hist_kernel(const int* __restrict__ seq, float* __restrict__ counts_out)
{
    const int t    = threadIdx.x;
    const int wave = t >> 6;
    const int lane = t & 63;
    const long long r0 = (long long)blockIdx.x * HROWS;

    __shared__ unsigned long long part[HROWS][4];

    unsigned long long c0 = 0ull, c1 = 0ull;
    {
        const int4* p0 = reinterpret_cast<const int4*>(seq + r0 * Lc);
        const int4* p1 = reinterpret_cast<const int4*>(seq + (r0 + 1) * Lc);
        #pragma unroll
        for (int i = 0; i < Lc / 4 / 256; ++i) {      // 4 iters, int4 each
            const int4 a = p0[i * 256 + t];
            const int4 b = p1[i * 256 + t];
            c0 += 1ull << (((unsigned)a.x & 3u) << 4);
            c0 += 1ull << (((unsigned)a.y & 3u) << 4);
            c0 += 1ull << (((unsigned)a.z & 3u) << 4);
            c0 += 1ull << (((unsigned)a.w & 3u) << 4);
            c1 += 1ull << (((unsigned)b.x & 3u) << 4);
            c1 += 1ull << (((unsigned)b.y & 3u) << 4);
            c1 += 1ull << (((unsigned)b.z & 3u) << 4);
            c1 += 1ull << (((unsigned)b.w & 3u) << 4);
        }
    }
    #pragma unroll
    for (int off = 32; off > 0; off >>= 1) {
        c0 += __shfl_down(c0, off);
        c1 += __shfl_down(c1, off);
    }
    if (lane == 0) { part[0][wave] = c0; part[1][wave] = c1; }
    __syncthreads();

    if (t < HROWS * 4) {
        const int rw = t >> 2, a = t & 3;
        const unsigned long long s =
            part[rw][0] + part[rw][1] + part[rw][2] + part[rw][3];
        // counts for row r live at out[r*Dc + a], a = 0..3 (scratch)
        counts_out[(r0 + rw) * Dc + a] =
            (float)((unsigned)((s >> (a * 16)) & 0xFFFFull));
    }
}

// ---------------- Kernel 2: affine + 2-layer MLP ----------------
static constexpr int RPB = 8;   // rows per block

__global__ __launch_bounds__(256, 2)
void mlp_kernel(
    const float* __restrict__ baseline,   // [B, D]
    const float* __restrict__ char_scales,// [A]
    const float* __restrict__ dim_w,      // [D]
    const float* __restrict__ sk_bias,    // [D]
    const float* __restrict__ mods,       // [A, D]
    const float* __restrict__ W1,         // [D, D]
    const float* __restrict__ b1,         // [D]
    const float* __restrict__ W2,         // [D, D]
    const float* __restrict__ b2,         // [D]
    float*       __restrict__ out)        // [B, D]; cols 0..3 hold counts on entry
{
    __shared__ __align__(16) float e_lds[RPB][Dc];
    __shared__ __align__(16) float h_lds[RPB][Dc];
    __shared__ __align__(16) float psum[4][RPB][Dc];

    const int t    = threadIdx.x;
    const int r0   = blockIdx.x * RPB;
    const int j    = t & (Dc - 1);   // 0..127
    const int half = t >> 7;         // 0 or 1
    const float invL = 1.0f / (float)Lc;

    // ---- Phase 2: e = (baseline*dw + bias)*scale + mods -> LDS ----
    {
        const float s0 = char_scales[0], s1 = char_scales[1],
                    s2 = char_scales[2], s3 = char_scales[3];
        const float dwj = dim_w[j], bj = sk_bias[j];
        const float m0 = mods[0 * Dc + j], m1 = mods[1 * Dc + j],
                    m2 = mods[2 * Dc + j], m3 = mods[3 * Dc + j];
        #pragma unroll
        for (int rr = 0; rr < RPB / 2; ++rr) {
            const int r = half + rr * 2;
            const float* cp = out + (long long)(r0 + r) * Dc;  // counts scratch
            const float c0 = cp[0], c1 = cp[1], c2 = cp[2], c3 = cp[3];
            const float scale = (c0 * s0 + c1 * s1 + c2 * s2 + c3 * s3) * invL;
            const float md    = (c0 * m0 + c1 * m1 + c2 * m2 + c3 * m3) * invL;
            const float base  = baseline[(long long)(r0 + r) * Dc + j];
            e_lds[r][j] = (base * dwj + bj) * scale + md;
        }
    }
    __syncthreads();

    // Thread mapping for GEMM phases: wave id q = k-quarter, lane jg owns
    // output columns {jg, jg+64}. e-broadcast reads reused across both.
    const int q  = t >> 6;           // 0..3 -> k in [q*32, q*32+32)
    const int jg = t & 63;
    const int k0 = q * 32;

    // ---- Phase 3: h = relu(e @ W1^T + b1) ----
    {
        float a0[RPB], a1[RPB];
        #pragma unroll
        for (int r = 0; r < RPB; ++r) { a0[r] = 0.f; a1[r] = 0.f; }
        const float4* w0 = reinterpret_cast<const float4*>(W1 + jg * Dc + k0);
        const float4* w1 = reinterpret_cast<const float4*>(W1 + (jg + 64) * Dc + k0);
        #pragma unroll
        for (int kk = 0; kk < 8; ++kk) {
            const float4 wa = w0[kk];
            const float4 wb = w1[kk];
            #pragma unroll
            for (int r = 0; r < RPB; ++r) {
                const float4 e = *reinterpret_cast<const float4*>(&e_lds[r][k0 + kk * 4]);
                a0[r] += wa.x * e.x + wa.y * e.y + wa.z * e.z + wa.w * e.w;
                a1[r] += wb.x * e.x + wb.y * e.y + wb.z * e.z + wb.w * e.w;
            }
        }
        #pragma unroll
        for (int r = 0; r < RPB; ++r) {
            psum[q][r][jg]      = a0[r];
            psum[q][r][jg + 64] = a1[r];
        }
    }
    __syncthreads();
    {
        const float b = b1[j];
        #pragma unroll
        for (int rr = 0; rr < RPB / 2; ++rr) {
            const int r = half + rr * 2;
            const float h = b + psum[0][r][j] + psum[1][r][j]
                              + psum[2][r][j] + psum[3][r][j];
            h_lds[r][j] = h > 0.0f ? h : 0.0f;
        }
    }
    __syncthreads();

    // ---- Phase 4: out = h @ W2^T + b2 ----
    {
        float a0[RPB], a1[RPB];
        #pragma unroll
        for (int r = 0; r < RPB; ++r) { a0[r] = 0.f; a1[r] = 0.f; }
        const float4* w0 = reinterpret_cast<const float4*>(W2 + jg * Dc + k0);
        const float4* w1 = reinterpret_cast<const float4*>(W2 + (jg + 64) * Dc + k0);
        #pragma unroll
        for (int kk = 0; kk < 8; ++kk) {
            const float4 wa = w0[kk];
            const float4 wb = w1[kk];
            #pragma unroll
            for (int r = 0; r < RPB; ++r) {
                const float4 h = *reinterpret_cast<const float4*>(&h_lds[r][k0 + kk * 4]);
                a0[r] += wa.x * h.x + wa.y * h.y + wa.z * h.z + wa.w * h.w;
                a1[r] += wb.x * h.x + wb.y * h.y + wb.z * h.z + wb.w * h.w;
            }
        }
        #pragma unroll
        for (int r = 0; r < RPB; ++r) {
            psum[q][r][jg]      = a0[r];
            psum[q][r][jg + 64] = a1[r];
        }
    }
    __syncthreads();
    {
        const float b = b2[j];
        #pragma unroll
        for (int rr = 0; rr < RPB / 2; ++rr) {
            const int r = half + rr * 2;
            out[(long long)(r0 + r) * Dc + j] = b + psum[0][r][j] + psum[1][r][j]
                                                  + psum[2][r][j] + psum[3][r][j];
        }
    }
}

extern "C" void kernel_launch(void* const* d_in, const int* in_sizes, int n_in,
                              void* d_out, int out_size, void* d_ws, size_t ws_size,
                              hipStream_t stream) {
    const int*   seq         = (const int*)  d_in[0];
    const float* baseline    = (const float*)d_in[1];
    const float* char_scales = (const float*)d_in[2];
    const float* dim_w       = (const float*)d_in[3];
    const float* sk_bias     = (const float*)d_in[4];
    const float* mods        = (const float*)d_in[5];
    const float* W1          = (const float*)d_in[6];
    const float* b1          = (const float*)d_in[7];
    const float* W2          = (const float*)d_in[8];
    const float* b2          = (const float*)d_in[9];
    float*       out         = (float*)d_out;

    const int B = in_sizes[1] / Dc;          // 4096

    // Dispatch 1: histogram -> counts stashed in out[:, 0:4]
    hipLaunchKernelGGL(hist_kernel, dim3(B / HROWS), dim3(256), 0, stream,
                       seq, out);
    // Dispatch 2: affine + MLP (stream-ordered after hist)
    hipLaunchKernelGGL(mlp_kernel, dim3(B / RPB), dim3(256), 0, stream,
                       baseline, char_scales, dim_w, sk_bias, mods,
                       W1, b1, W2, b2, out);
}

// Round 2
// 116.964 us; speedup vs baseline: 1.0285x; 1.0285x over previous
//
#include <hip/hip_runtime.h>

// FixedLearnableTensorSketch: B=4096, L=4096, A=4, D=128.
//
// R6: kernel-side time is now a minority of dur_us. R5's counters proved
// dur_us (120.3) includes >= 40 us of harness poison-fill/restore time:
// top-5 dispatches are all 268 MB fillBufferAligned at 6.5 TB/s (41 us
// each), and neither of our kernels makes the cutoff -> each < 40.7 us,
// sum < 81 us < dur_us. Remaining controllable cost ~= hist stream
// (~11-14 us at stream BW) + mlp (~6-8 us, LDS-pipe-bound).
//
// R6 change: mlp GEMM phases move from 4-way k-split x 2 cols/thread to
// 8-way k-split x 4 cols/thread. The dominant LDS cost (broadcast
// ds_read_b128 of e_lds / h_lds) halves: 64 -> 32 reads/thread/phase.
// psum grows to [8][RPB][128] = 32 KiB; total LDS 40 KiB -> still 2
// blocks/CU. All LDS patterns stay <= 2-way bank aliasing (free).
// hist_kernel unchanged (already ~stream-BW-bound).

static constexpr int Lc = 4096;
static constexpr int Ac = 4;
static constexpr int Dc = 128;

// ---------------- Kernel 1: per-row histogram ----------------
// 2 rows per block, 256 threads. Packed 4x16-bit counters in a u64:
// per-thread field max = 16, per-row total 4096 < 2^16.
static constexpr int HROWS = 2;

__global__ __launch_bounds__(256, 4)
void hist_kernel(const int* __restrict__ seq, float* __restrict__ counts_out)
{
    const int t    = threadIdx.x;
    const int wave = t >> 6;
    const int lane = t & 63;
    const long long r0 = (long long)blockIdx.x * HROWS;

    __shared__ unsigned long long part[HROWS][4];

    unsigned long long c0 = 0ull, c1 = 0ull;
    {
        const int4* p0 = reinterpret_cast<const int4*>(seq + r0 * Lc);
        const int4* p1 = reinterpret_cast<const int4*>(seq + (r0 + 1) * Lc);
        #pragma unroll
        for (int i = 0; i < Lc / 4 / 256; ++i) {      // 4 iters, int4 each
            const int4 a = p0[i * 256 + t];
            const int4 b = p1[i * 256 + t];
            c0 += 1ull << (((unsigned)a.x & 3u) << 4);
            c0 += 1ull << (((unsigned)a.y & 3u) << 4);
            c0 += 1ull << (((unsigned)a.z & 3u) << 4);
            c0 += 1ull << (((unsigned)a.w & 3u) << 4);
            c1 += 1ull << (((unsigned)b.x & 3u) << 4);
            c1 += 1ull << (((unsigned)b.y & 3u) << 4);
            c1 += 1ull << (((unsigned)b.z & 3u) << 4);
            c1 += 1ull << (((unsigned)b.w & 3u) << 4);
        }
    }
    #pragma unroll
    for (int off = 32; off > 0; off >>= 1) {
        c0 += __shfl_down(c0, off);
        c1 += __shfl_down(c1, off);
    }
    if (lane == 0) { part[0][wave] = c0; part[1][wave] = c1; }
    __syncthreads();

    if (t < HROWS * 4) {
        const int rw = t >> 2, a = t & 3;
        const unsigned long long s =
            part[rw][0] + part[rw][1] + part[rw][2] + part[rw][3];
        // counts for row r live at out[r*Dc + a], a = 0..3 (scratch)
        counts_out[(r0 + rw) * Dc + a] =
            (float)((unsigned)((s >> (a * 16)) & 0xFFFFull));
    }
}

// ---------------- Kernel 2: affine + 2-layer MLP ----------------
static constexpr int RPB = 8;   // rows per block

__global__ __launch_bounds__(256, 2)
void mlp_kernel(
    const float* __restrict__ baseline,   // [B, D]
    const float* __restrict__ char_scales,// [A]
    const float* __restrict__ dim_w,      // [D]
    const float* __restrict__ sk_bias,    // [D]
    const float* __restrict__ mods,       // [A, D]
    const float* __restrict__ W1,         // [D, D]
    const float* __restrict__ b1,         // [D]
    const float* __restrict__ W2,         // [D, D]
    const float* __restrict__ b2,         // [D]
    float*       __restrict__ out)        // [B, D]; cols 0..3 hold counts on entry
{
    __shared__ __align__(16) float e_lds[RPB][Dc];
    __shared__ __align__(16) float h_lds[RPB][Dc];
    __shared__ __align__(16) float psum[8][RPB][Dc];   // 32 KiB

    const int t    = threadIdx.x;
    const int r0   = blockIdx.x * RPB;
    const int j    = t & (Dc - 1);   // 0..127
    const int half = t >> 7;         // 0 or 1
    const float invL = 1.0f / (float)Lc;

    // ---- Phase 2: e = (baseline*dw + bias)*scale + mods -> LDS ----
    {
        const float s0 = char_scales[0], s1 = char_scales[1],
                    s2 = char_scales[2], s3 = char_scales[3];
        const float dwj = dim_w[j], bj = sk_bias[j];
        const float m0 = mods[0 * Dc + j], m1 = mods[1 * Dc + j],
                    m2 = mods[2 * Dc + j], m3 = mods[3 * Dc + j];
        #pragma unroll
        for (int rr = 0; rr < RPB / 2; ++rr) {
            const int r = half + rr * 2;
            const float* cp = out + (long long)(r0 + r) * Dc;  // counts scratch
            const float c0 = cp[0], c1 = cp[1], c2 = cp[2], c3 = cp[3];
            const float scale = (c0 * s0 + c1 * s1 + c2 * s2 + c3 * s3) * invL;
            const float md    = (c0 * m0 + c1 * m1 + c2 * m2 + c3 * m3) * invL;
            const float base  = baseline[(long long)(r0 + r) * Dc + j];
            e_lds[r][j] = (base * dwj + bj) * scale + md;
        }
    }
    __syncthreads();

    // GEMM thread mapping: q = t>>5 (k-eighth, k in [q*16, q*16+16)),
    // jg = t&31 owns output columns {jg, jg+32, jg+64, jg+96}.
    // Broadcast e-reads reused across 4 columns: 32 ds_read_b128/thread/phase.
    const int q  = t >> 5;           // 0..7
    const int jg = t & 31;
    const int k0 = q * 16;

    // ---- Phase 3: h = relu(e @ W1^T + b1) ----
    {
        float a0[RPB], a1[RPB], a2[RPB], a3[RPB];
        #pragma unroll
        for (int r = 0; r < RPB; ++r) { a0[r] = 0.f; a1[r] = 0.f; a2[r] = 0.f; a3[r] = 0.f; }
        const float4* w0 = reinterpret_cast<const float4*>(W1 + (jg     ) * Dc + k0);
        const float4* w1 = reinterpret_cast<const float4*>(W1 + (jg + 32) * Dc + k0);
        const float4* w2 = reinterpret_cast<const float4*>(W1 + (jg + 64) * Dc + k0);
        const float4* w3 = reinterpret_cast<const float4*>(W1 + (jg + 96) * Dc + k0);
        #pragma unroll
        for (int kk = 0; kk < 4; ++kk) {
            const float4 wa = w0[kk];
            const float4 wb = w1[kk];
            const float4 wc = w2[kk];
            const float4 wd = w3[kk];
            #pragma unroll
            for (int r = 0; r < RPB; ++r) {
                const float4 e = *reinterpret_cast<const float4*>(&e_lds[r][k0 + kk * 4]);
                a0[r] += wa.x * e.x + wa.y * e.y + wa.z * e.z + wa.w * e.w;
                a1[r] += wb.x * e.x + wb.y * e.y + wb.z * e.z + wb.w * e.w;
                a2[r] += wc.x * e.x + wc.y * e.y + wc.z * e.z + wc.w * e.w;
                a3[r] += wd.x * e.x + wd.y * e.y + wd.z * e.z + wd.w * e.w;
            }
        }
        #pragma unroll
        for (int r = 0; r < RPB; ++r) {
            psum[q][r][jg     ] = a0[r];
            psum[q][r][jg + 32] = a1[r];
            psum[q][r][jg + 64] = a2[r];
            psum[q][r][jg + 96] = a3[r];
        }
    }
    __syncthreads();
    {
        const float b = b1[j];
        #pragma unroll
        for (int rr = 0; rr < RPB / 2; ++rr) {
            const int r = half + rr * 2;
            float s = b;
            #pragma unroll
            for (int qq = 0; qq < 8; ++qq) s += psum[qq][r][j];
            h_lds[r][j] = s > 0.0f ? s : 0.0f;
        }
    }
    __syncthreads();

    // ---- Phase 4: out = h @ W2^T + b2 (same mapping) ----
    {
        float a0[RPB], a1[RPB], a2[RPB], a3[RPB];
        #pragma unroll
        for (int r = 0; r < RPB; ++r) { a0[r] = 0.f; a1[r] = 0.f; a2[r] = 0.f; a3[r] = 0.f; }
        const float4* w0 = reinterpret_cast<const float4*>(W2 + (jg     ) * Dc + k0);
        const float4* w1 = reinterpret_cast<const float4*>(W2 + (jg + 32) * Dc + k0);
        const float4* w2 = reinterpret_cast<const float4*>(W2 + (jg + 64) * Dc + k0);
        const float4* w3 = reinterpret_cast<const float4*>(W2 + (jg + 96) * Dc + k0);
        #pragma unroll
        for (int kk = 0; kk < 4; ++kk) {
            const float4 wa = w0[kk];
            const float4 wb = w1[kk];
            const float4 wc = w2[kk];
            const float4 wd = w3[kk];
            #pragma unroll
            for (int r = 0; r < RPB; ++r) {
                const float4 h = *reinterpret_cast<const float4*>(&h_lds[r][k0 + kk * 4]);
                a0[r] += wa.x * h.x + wa.y * h.y + wa.z * h.z + wa.w * h.w;
                a1[r] += wb.x * h.x + wb.y * h.y + wb.z * h.z + wb.w * h.w;
                a2[r] += wc.x * h.x + wc.y * h.y + wc.z * h.z + wc.w * h.w;
                a3[r] += wd.x * h.x + wd.y * h.y + wd.z * h.z + wd.w * h.w;
            }
        }
        #pragma unroll
        for (int r = 0; r < RPB; ++r) {
            psum[q][r][jg     ] = a0[r];
            psum[q][r][jg + 32] = a1[r];
            psum[q][r][jg + 64] = a2[r];
            psum[q][r][jg + 96] = a3[r];
        }
    }
    __syncthreads();
    {
        const float b = b2[j];
        #pragma unroll
        for (int rr = 0; rr < RPB / 2; ++rr) {
            const int r = half + rr * 2;
            float s = b;
            #pragma unroll
            for (int qq = 0; qq < 8; ++qq) s += psum[qq][r][j];
            out[(long long)(r0 + r) * Dc + j] = s;
        }
    }
}

extern "C" void kernel_launch(void* const* d_in, const int* in_sizes, int n_in,
                              void* d_out, int out_size, void* d_ws, size_t ws_size,
                              hipStream_t stream) {
    const int*   seq         = (const int*)  d_in[0];
    const float* baseline    = (const float*)d_in[1];
    const float* char_scales = (const float*)d_in[2];
    const float* dim_w       = (const float*)d_in[3];
    const float* sk_bias     = (const float*)d_in[4];
    const float* mods        = (const float*)d_in[5];
    const float* W1          = (const float*)d_in[6];
    const float* b1          = (const float*)d_in[7];
    const float* W2          = (const float*)d_in[8];
    const float* b2          = (const float*)d_in[9];
    float*       out         = (float*)d_out;

    const int B = in_sizes[1] / Dc;          // 4096

    // Dispatch 1: histogram -> counts stashed in out[:, 0:4]
    hipLaunchKernelGGL(hist_kernel, dim3(B / HROWS), dim3(256), 0, stream,
                       seq, out);
    // Dispatch 2: affine + MLP (stream-ordered after hist)
    hipLaunchKernelGGL(mlp_kernel, dim3(B / RPB), dim3(256), 0, stream,
                       baseline, char_scales, dim_w, sk_bias, mods,
                       W1, b1, W2, b2, out);
}